// Round 1
// baseline (12.098 us; speedup 1.0000x reference)
//
#include <hip/hip_runtime.h>

// Problem constants from the reference (fixed problem instance).
#define BB 32      // batch
#define KK 8       // channels
#define HH 512     // height
#define WW 512     // width
#define SS 50      // sample count
#define HID 64     // hidden dim
#define CTX 71     // 9*K - 1

// One 64-thread block (one wave) per (b, s) pair.
// Lane h owns hidden unit h. 72 gathered values staged in LDS.
__global__ void __launch_bounds__(64)
le_core_kernel(const float* __restrict__ z,
               const float* __restrict__ W1,
               const float* __restrict__ b1,
               const float* __restrict__ W2,
               const float* __restrict__ b2,
               const int*   __restrict__ b_idx,
               const int*   __restrict__ i_idx,
               const int*   __restrict__ j_idx,
               float*       __restrict__ ws)
{
    const int bs = blockIdx.x;          // 0 .. BB*SS-1
    const int b  = bs / SS;
    const int s  = bs % SS;
    const int h  = threadIdx.x;         // 0 .. 63

    __shared__ float full[9 * KK];      // 72 gathered values

    const int i0   = i_idx[s];
    const int j0   = j_idx[s];
    const int bsel = b_idx[s];
    const int rm   = 4 * KK + bsel;     // removed (center) position

    // Cooperative gather: p = n*K + k, n in [0,9), k in [0,K)
    for (int p = h; p < 9 * KK; p += 64) {
        const int n  = p >> 3;          // K == 8
        const int k  = p & 7;
        const int ni = (i0 + (n / 3) - 1) & (HH - 1);   // torus wrap, H pow2
        const int nj = (j0 + (n % 3) - 1) & (WW - 1);
        full[p] = z[(((b * KK + k) * HH + ni) * WW) + nj];
    }
    __syncthreads();

    // Matvec: lane h computes hidden unit h over the 71 kept elements.
    float acc = b1[h];
    #pragma unroll 8
    for (int t = 0; t < CTX; ++t) {
        const int src = t + (t >= rm ? 1 : 0);  // skip removed element
        acc = fmaf(full[src], W1[t * HID + h], acc);  // LDS broadcast + coalesced W1
    }
    const float hv      = acc > 0.0f ? acc : 0.0f;     // relu
    float       contrib = hv * W2[h];

    // Wave-64 reduction of the output dot product.
    #pragma unroll
    for (int off = 32; off > 0; off >>= 1)
        contrib += __shfl_down(contrib, off);

    if (h == 0) {
        const float logit  = contrib + b2[0];
        const float pred   = logit > 0.0f ? 1.0f : 0.0f;
        const float actual = full[rm];                  // z[b, b_idx, i, j]
        ws[bs] = (pred != actual) ? 1.0f : 0.0f;
    }
}

// Single-block reduction of the 1600 per-pair error flags -> mean.
__global__ void __launch_bounds__(256)
le_reduce_kernel(const float* __restrict__ ws, float* __restrict__ out)
{
    const int tid = threadIdx.x;
    float s = 0.0f;
    for (int i = tid; i < BB * SS; i += 256) s += ws[i];

    #pragma unroll
    for (int off = 32; off > 0; off >>= 1)
        s += __shfl_down(s, off);

    __shared__ float wsum[4];
    if ((tid & 63) == 0) wsum[tid >> 6] = s;
    __syncthreads();
    if (tid == 0) {
        const float total = wsum[0] + wsum[1] + wsum[2] + wsum[3];
        out[0] = total * (1.0f / (float)(BB * SS));
    }
}

extern "C" void kernel_launch(void* const* d_in, const int* in_sizes, int n_in,
                              void* d_out, int out_size, void* d_ws, size_t ws_size,
                              hipStream_t stream)
{
    const float* z     = (const float*)d_in[0];
    const float* W1    = (const float*)d_in[1];
    const float* b1    = (const float*)d_in[2];
    const float* W2    = (const float*)d_in[3];
    const float* b2    = (const float*)d_in[4];
    const int*   b_idx = (const int*)d_in[5];
    const int*   i_idx = (const int*)d_in[6];
    const int*   j_idx = (const int*)d_in[7];

    float* out = (float*)d_out;
    float* ws  = (float*)d_ws;   // BB*SS floats = 6.4 KB scratch

    le_core_kernel<<<BB * SS, 64, 0, stream>>>(z, W1, b1, W2, b2,
                                               b_idx, i_idx, j_idx, ws);
    le_reduce_kernel<<<1, 256, 0, stream>>>(ws, out);
}